// Round 8
// baseline (330.070 us; speedup 1.0000x reference)
//
#include <hip/hip_runtime.h>

#define B_ 4
#define N_ 8192
#define DIN 64
#define HDIM 64
#define DOUT 128
#define KNN 16
#define NBUCK 2048
#define QPB 16               // queries per block (kNN kernel)
#define QPW 4                // queries per wave
#define NTHR 256
#define BUFS 64              // survivor-buffer slots per query
#define NBATCH (N_ / 64)     // 128

__device__ __forceinline__ int mbcnt64(unsigned long long m) {
  return __builtin_amdgcn_mbcnt_hi((unsigned)(m >> 32),
         __builtin_amdgcn_mbcnt_lo((unsigned)m, 0));
}
// monotone float->uint map (total order, negatives below positives)
__device__ __forceinline__ unsigned mapkey(float d) {
  unsigned u = __float_as_uint(d);
  return (d < 0.0f) ? ~u : (u | 0x80000000u);
}
__device__ __forceinline__ float rf(float x) {  // force wave-uniform into SGPR
  return __int_as_float(__builtin_amdgcn_readfirstlane(__float_as_int(x)));
}

// Wave-cooperative exact 16 smallest by (key, original idx) among cnt slots.
// gout==null: compact kept 16 to slots 0..15, return kth distance (unmapped).
// gout!=null: write kept original idx to gout[rank] (global).
__device__ __forceinline__
float select16(unsigned* skQ, unsigned short* siQ, int cnt, unsigned short* gout) {
  const int l = threadIdx.x & 63;
  unsigned k = 0xFFFFFFFFu;
  unsigned mi = 0xFFFFu;
  if (l < cnt) { k = skQ[l]; mi = siQ[l]; }
  // radix-select 16th smallest key (bitwise, MSB->LSB)
  unsigned p = 0; int r = KNN;
  for (int bit = 31; bit >= 0; bit--) {
    unsigned long long ml = __ballot((int)(((k ^ p) >> bit) == 0u));
    int c0 = __popcll(ml);
    if (r > c0) { p |= (1u << bit); r -= c0; }
  }
  bool isLT = (k < p), isTie = (k == p);
  int tieC = __popcll(__ballot((int)isTie));
  bool keepT = isTie;
  if (tieC != r) {  // break ties at the kth value by smallest ORIGINAL index
    unsigned mk = isTie ? mi : 0xFFFFFFFFu;
    unsigned p2 = 0; int r2 = r;
    for (int bit = 15; bit >= 0; bit--) {
      unsigned long long ml = __ballot((int)(((mk ^ p2) >> bit) == 0u));
      int c0 = __popcll(ml);
      if (r2 > c0) { p2 |= (1u << bit); r2 -= c0; }
    }
    keepT = isTie && (mi <= p2);
  }
  bool keep = isLT || keepT;
  unsigned long long km = __ballot((int)keep);
  int rank = mbcnt64(km);
  if (gout) {
    if (keep) gout[rank] = mi;
  } else {
    if (keep) { skQ[rank] = k; siQ[rank] = mi; }
  }
  unsigned fb = (p & 0x80000000u) ? (p & 0x7FFFFFFFu) : ~p;  // unmap
  return __uint_as_float(fb);
}

// ---------------- Kernel A: counting-sort by x + compose affine params ----------
// blocks 0..3: sort batch b -> pk4[(x,y,z,sq)] + sid (original idx), x-ascending
// block 4:     compose M3 = w3@w2@w1 etc -> prm (A|D, B|C per channel)
__global__ __launch_bounds__(1024) void k_sort(
    const float* __restrict__ xyz,
    const float* __restrict__ w1, const float* __restrict__ b1,
    const float* __restrict__ w2, const float* __restrict__ b2,
    const float* __restrict__ w3, const float* __restrict__ b3,
    float4* __restrict__ pk4, unsigned short* __restrict__ sid,
    float4* __restrict__ prm) {
  const int t = threadIdx.x;
  __shared__ unsigned histA[NBUCK];
  __shared__ unsigned histB[NBUCK];
  __shared__ float rmm[32];

  if (blockIdx.x == 4) {  // ---- param composition ----
    float* M2 = (float*)histA;            // [64][10] floats
    float* bbv = (float*)histB;           // [64]
    if (t < HDIM) {
      float r[10];
#pragma unroll
      for (int c = 0; c < 10; c++) r[c] = 0.f;
      float s = b2[t];
      for (int l = 0; l < HDIM; l++) {
        float w = w2[t * HDIM + l];
#pragma unroll
        for (int c = 0; c < 10; c++) r[c] = fmaf(w, w1[l * 10 + c], r[c]);
        s = fmaf(w, b1[l], s);
      }
#pragma unroll
      for (int c = 0; c < 10; c++) M2[t * 10 + c] = r[c];
      bbv[t] = s;
    }
    __syncthreads();
    if (t < HDIM) {
      float r3[10];
#pragma unroll
      for (int c = 0; c < 10; c++) r3[c] = 0.f;
      float bc = b3[t];
      for (int l = 0; l < HDIM; l++) {
        float w = w3[t * HDIM + l];
#pragma unroll
        for (int c = 0; c < 10; c++) r3[c] = fmaf(w, M2[l * 10 + c], r3[c]);
        bc = fmaf(w, bbv[l], bc);
      }
      prm[t]      = make_float4(r3[0] - r3[6], r3[1] - r3[7], r3[2] - r3[8], bc);
      prm[64 + t] = make_float4(r3[3] + r3[6], r3[4] + r3[7], r3[5] + r3[8], r3[9]);
    }
    return;
  }

  // ---- sort batch b ----
  const int b = blockIdx.x;
  const float* xb = xyz + (size_t)b * 3 * N_;
  float xs[8];
  float lmin = 1e30f, lmax = -1e30f;
#pragma unroll
  for (int r = 0; r < 8; r++) {
    xs[r] = xb[r * 1024 + t];
    lmin = fminf(lmin, xs[r]); lmax = fmaxf(lmax, xs[r]);
  }
  for (int off = 32; off; off >>= 1) {
    lmin = fminf(lmin, __shfl_xor(lmin, off));
    lmax = fmaxf(lmax, __shfl_xor(lmax, off));
  }
  const int wid = t >> 6;
  if ((t & 63) == 0) { rmm[wid] = lmin; rmm[16 + wid] = lmax; }
  histA[t] = 0; histA[t + 1024] = 0;
  __syncthreads();
  if (t == 0) {
    float mn = rmm[0], mx = rmm[16];
    for (int w = 1; w < 16; w++) { mn = fminf(mn, rmm[w]); mx = fmaxf(mx, rmm[16 + w]); }
    rmm[0] = mn; rmm[16] = mx;
  }
  __syncthreads();
  const float mn = rmm[0];
  const float range = rmm[16] - mn;
  const float scale = (range > 0.f) ? ((float)NBUCK / range) : 0.f;
  int bk[8];
#pragma unroll
  for (int r = 0; r < 8; r++) {
    int v = (int)((xs[r] - mn) * scale);
    bk[r] = v > (NBUCK - 1) ? (NBUCK - 1) : (v < 0 ? 0 : v);
    atomicAdd(&histA[bk[r]], 1u);
  }
  __syncthreads();
  // exclusive scan (Hillis-Steele ping-pong)
  unsigned* src = histA; unsigned* dst = histB;
  for (int off = 1; off < NBUCK; off <<= 1) {
    for (int i = t; i < NBUCK; i += 1024) {
      unsigned v = src[i];
      if (i >= off) v += src[i - off];
      dst[i] = v;
    }
    __syncthreads();
    unsigned* tmp = src; src = dst; dst = tmp;
  }
  for (int i = t; i < NBUCK; i += 1024) dst[i] = i ? src[i - 1] : 0u;
  __syncthreads();
  // scatter
#pragma unroll
  for (int r = 0; r < 8; r++) {
    int m = r * 1024 + t;
    float x = xs[r], y = xb[N_ + m], z = xb[2 * N_ + m];
    float sq = __fadd_rn(__fadd_rn(__fmul_rn(x, x), __fmul_rn(y, y)), __fmul_rn(z, z));
    unsigned pos = atomicAdd(&dst[bk[r]], 1u);
    pk4[((size_t)b << 13) + pos] = make_float4(x, y, z, sq);
    sid[((size_t)b << 13) + pos] = (unsigned short)m;
  }
}

// ---------------- Kernel B: windowed exact kNN over x-sorted points -------------
// Wave owns 4 consecutive x-sorted queries (state in SGPRs). Expanding window
// of 64-candidate batches; a side closes when (x-edge gap)^2 > max tau (exact
// lower bound, 1.0001 margin for fp rounding; strict > keeps dist==tau ties).
__global__ __launch_bounds__(NTHR, 6) void k_knn(
    const float4* __restrict__ pk4, const unsigned short* __restrict__ sid,
    unsigned short* __restrict__ fidxG) {
  const int blk = blockIdx.x;
  const int b  = blk >> 9;
  const int s0 = (blk & 511) << 4;      // sorted-position base of this block
  const int t = threadIdx.x;
  const int lane = t & 63;
  const int j = __builtin_amdgcn_readfirstlane(t >> 6);
  const float4* pkb = pk4 + ((size_t)b << 13);
  const unsigned short* sdb = sid + ((size_t)b << 13);
  const float INF = __uint_as_float(0x7f800000u);

  __shared__ unsigned skey[QPB * BUFS];        // 4 KB (rows owned per-wave)
  __shared__ unsigned short sidxS[QPB * BUFS]; // 2 KB

  float qX[QPW], qY[QPW], qZ[QPW], qS[QPW]; int qN[QPW];
#pragma unroll
  for (int i = 0; i < QPW; i++) {
    int p = s0 + j * QPW + i;
    float4 qv = pkb[p];
    qX[i] = rf(qv.x); qY[i] = rf(qv.y); qZ[i] = rf(qv.z); qS[i] = rf(qv.w);
    qN[i] = __builtin_amdgcn_readfirstlane((int)sdb[p]);
  }
  const float qxmin = fminf(fminf(qX[0], qX[1]), fminf(qX[2], qX[3]));
  const float qxmax = fmaxf(fmaxf(qX[0], qX[1]), fmaxf(qX[2], qX[3]));
  float tauF[QPW]; int cntA[QPW];

  const int start = (s0 + j * QPW) >> 6;
  {  // unconditional fill from the home batch, then first exact tau
    float4 c = pkb[start * 64 + lane];
    unsigned short mid = sdb[start * 64 + lane];
#pragma unroll
    for (int i = 0; i < QPW; i++) {
      float dot = fmaf(c.z, qZ[i], fmaf(c.y, qY[i], __fmul_rn(c.x, qX[i])));
      float d = fmaf(-2.0f, dot, __fadd_rn(qS[i], c.w));
      skey[(j * QPW + i) * BUFS + lane] = mapkey(d);
      sidxS[(j * QPW + i) * BUFS + lane] = mid;
    }
#pragma unroll
    for (int i = 0; i < QPW; i++) {
      tauF[i] = rf(select16(skey + (j * QPW + i) * BUFS,
                            sidxS + (j * QPW + i) * BUFS, BUFS, nullptr));
      cntA[i] = KNN;
    }
  }

  int bl = start - 1, br = start + 1;
  for (;;) {
    bool lo = (bl >= 0), ro = (br < NBATCH);
    if (!(lo | ro)) break;
    float tmax = fmaxf(fmaxf(tauF[0], tauF[1]), fmaxf(tauF[2], tauF[3])) * 1.0001f;
    float dl = INF, dr = INF;
    if (lo) {
      float e = pkb[bl * 64 + 63].x;           // left batch's max x
      dl = __fsub_rn(qxmin, e);
      if (dl > 0.f && __fmul_rn(dl, dl) > tmax) { lo = false; bl = -1; }
    }
    if (ro) {
      float e = pkb[br * 64].x;                // right batch's min x
      dr = __fsub_rn(e, qxmax);
      if (dr > 0.f && __fmul_rn(dr, dr) > tmax) { ro = false; br = NBATCH; }
    }
    if (!(lo | ro)) break;
    int pb;
    if (lo && (!ro || dl <= dr)) { pb = bl; bl--; } else { pb = br; br++; }

    float4 c = pkb[pb * 64 + lane];
    unsigned short mid = sdb[pb * 64 + lane];
    float dd[QPW];
#pragma unroll
    for (int i = 0; i < QPW; i++) {
      float dot = fmaf(c.z, qZ[i], fmaf(c.y, qY[i], __fmul_rn(c.x, qX[i])));
      dd[i] = fmaf(-2.0f, dot, __fadd_rn(qS[i], c.w));
    }
#pragma unroll
    for (int i = 0; i < QPW; i++) {
      bool mine = dd[i] <= tauF[i];   // <= : out-of-order scan must keep ties
      unsigned long long hit = __ballot((int)mine);
      if (hit) {
        unsigned* skQ = skey + (j * QPW + i) * BUFS;
        unsigned short* siQ = sidxS + (j * QPW + i) * BUFS;
        int h = __popcll(hit);
        int rk = mbcnt64(hit);
        unsigned key = mapkey(dd[i]);
        if (cntA[i] + h <= BUFS) {  // fast path
          if (mine) { skQ[cntA[i] + rk] = key; siQ[cntA[i] + rk] = mid; }
          cntA[i] += h;
          if (cntA[i] == BUFS) {
            tauF[i] = rf(select16(skQ, siQ, BUFS, nullptr));
            cntA[i] = KNN;
          }
        } else {  // overflow: rounds, compacting as needed
          unsigned long long rem = hit; bool mrem = mine;
          while (rem) {
            int freeS = BUFS - cntA[i];
            int hh = __popcll(rem);
            int rr = mbcnt64(rem);
            bool wn = mrem && (rr < freeS);
            if (wn) { skQ[cntA[i] + rr] = key; siQ[cntA[i] + rr] = mid; }
            cntA[i] += (hh < freeS) ? hh : freeS;
            if (cntA[i] == BUFS) {
              tauF[i] = rf(select16(skQ, siQ, BUFS, nullptr));
              cntA[i] = KNN;
            }
            mrem = mrem && !wn && (dd[i] <= tauF[i]);
            rem = __ballot((int)mrem);
          }
        }
      }
    }
  }
  // final exact selection -> global neighbor ids at the ORIGINAL query slot
#pragma unroll
  for (int i = 0; i < QPW; i++) {
    select16(skey + (j * QPW + i) * BUFS, sidxS + (j * QPW + i) * BUFS,
             cntA[i], fidxG + ((((size_t)b << 13) + qN[i]) << 4));
  }
}

// ---------------- Kernel C: epilogue (gather, fe, shortcut GEMM, store) --------
__global__ __launch_bounds__(256, 8) void k_epi(
    const float* __restrict__ xyz, const float* __restrict__ feature,
    const float4* __restrict__ prm, const float* __restrict__ wsM,
    const float* __restrict__ bs, const unsigned short* __restrict__ fidxG,
    float* __restrict__ out) {
  const int blk = blockIdx.x;
  const int b  = blk >> 9;
  const int n0 = (blk & 511) << 4;
  const int t = threadIdx.x;
  const int q = t & 15;
  const int g = t >> 4;
  const float* xb = xyz + (size_t)b * 3 * N_;
  const float INF = __uint_as_float(0x7f800000u);

  __shared__ float nb[64 * 16];    // neighbor x/y/z/dsq rows
  __shared__ float feFe[64 * 16];  // fe channels
  __shared__ float feL[64 * 16];   // feature tile

  const float qx = xb[n0 + q], qy = xb[N_ + n0 + q], qz = xb[2 * N_ + n0 + q];
  {  // gather: thread handles neighbor slot k=g for query q
    int m = fidxG[((((size_t)b << 13) + n0 + q) << 4) + g];
    float x = xb[m], y = xb[N_ + m], z = xb[2 * N_ + m];
    float dx = __fsub_rn(x, qx), dy = __fsub_rn(y, qy), dz = __fsub_rn(z, qz);
    float dsq = __fadd_rn(__fadd_rn(__fmul_rn(dx, dx), __fmul_rn(dy, dy)),
                          __fmul_rn(dz, dz));
    nb[g * 16 + q] = x;
    nb[(16 + g) * 16 + q] = y;
    nb[(32 + g) * 16 + q] = z;
    nb[(48 + g) * 16 + q] = dsq;
  }
  __syncthreads();

  {  // fe: thread computes channels c = g*4..+3 for query q
    float mx0 = -INF, mx1 = -INF, mx2 = -INF, mx3 = -INF;
    const int c0 = g * 4;
    float4 pB0 = prm[64 + c0], pB1 = prm[64 + c0 + 1];
    float4 pB2 = prm[64 + c0 + 2], pB3 = prm[64 + c0 + 3];
#pragma unroll
    for (int k = 0; k < KNN; k++) {
      float nx = nb[k * 16 + q], ny = nb[(16 + k) * 16 + q];
      float nz = nb[(32 + k) * 16 + q], nd = nb[(48 + k) * 16 + q];
      mx0 = fmaxf(mx0, fmaf(nz, pB0.z, fmaf(ny, pB0.y, fmaf(nx, pB0.x, __fmul_rn(nd, pB0.w)))));
      mx1 = fmaxf(mx1, fmaf(nz, pB1.z, fmaf(ny, pB1.y, fmaf(nx, pB1.x, __fmul_rn(nd, pB1.w)))));
      mx2 = fmaxf(mx2, fmaf(nz, pB2.z, fmaf(ny, pB2.y, fmaf(nx, pB2.x, __fmul_rn(nd, pB2.w)))));
      mx3 = fmaxf(mx3, fmaf(nz, pB3.z, fmaf(ny, pB3.y, fmaf(nx, pB3.x, __fmul_rn(nd, pB3.w)))));
    }
    float4 pA0 = prm[c0], pA1 = prm[c0 + 1], pA2 = prm[c0 + 2], pA3 = prm[c0 + 3];
    feFe[(c0 + 0) * 16 + q] = fmaf(qz, pA0.z, fmaf(qy, pA0.y, fmaf(qx, pA0.x, pA0.w))) + mx0;
    feFe[(c0 + 1) * 16 + q] = fmaf(qz, pA1.z, fmaf(qy, pA1.y, fmaf(qx, pA1.x, pA1.w))) + mx1;
    feFe[(c0 + 2) * 16 + q] = fmaf(qz, pA2.z, fmaf(qy, pA2.y, fmaf(qx, pA2.x, pA2.w))) + mx2;
    feFe[(c0 + 3) * 16 + q] = fmaf(qz, pA3.z, fmaf(qy, pA3.y, fmaf(qx, pA3.x, pA3.w))) + mx3;
  }
#pragma unroll
  for (int ci = 0; ci < 4; ci++) {
    int c = g * 4 + ci;
    feL[c * 16 + q] = feature[(size_t)(b * DIN + c) * N_ + n0 + q];
  }
  __syncthreads();

  // shortcut GEMM: thread computes outputs o = g*8..+7 for query q
  float acc[8];
#pragma unroll
  for (int oi = 0; oi < 8; oi++) acc[oi] = 0.f;
  const float4* wsRow = (const float4*)(wsM + (size_t)g * 8 * DIN);
  for (int c4 = 0; c4 < DIN / 4; c4++) {
    float f0 = feL[(4 * c4 + 0) * 16 + q];
    float f1 = feL[(4 * c4 + 1) * 16 + q];
    float f2 = feL[(4 * c4 + 2) * 16 + q];
    float f3 = feL[(4 * c4 + 3) * 16 + q];
#pragma unroll
    for (int oi = 0; oi < 8; oi++) {
      float4 w = wsRow[oi * (DIN / 4) + c4];  // group-uniform, L1-resident
      acc[oi] = fmaf(w.x, f0, acc[oi]);
      acc[oi] = fmaf(w.y, f1, acc[oi]);
      acc[oi] = fmaf(w.z, f2, acc[oi]);
      acc[oi] = fmaf(w.w, f3, acc[oi]);
    }
  }
  float* ob = out + (size_t)b * DOUT * N_ + n0 + q;
#pragma unroll
  for (int oi = 0; oi < 8; oi++) {
    int o = g * 8 + oi;
    ob[(size_t)o * N_] = acc[oi] + bs[o] + feFe[(o & 63) * 16 + q];
  }
}

extern "C" void kernel_launch(void* const* d_in, const int* in_sizes, int n_in,
                              void* d_out, int out_size, void* d_ws, size_t ws_size,
                              hipStream_t stream) {
  const float* xyz     = (const float*)d_in[0];
  const float* feature = (const float*)d_in[1];
  const float* w1 = (const float*)d_in[2];
  const float* b1 = (const float*)d_in[3];
  const float* w2 = (const float*)d_in[4];
  const float* b2 = (const float*)d_in[5];
  const float* w3 = (const float*)d_in[6];
  const float* b3 = (const float*)d_in[7];
  const float* wsM = (const float*)d_in[8];
  const float* bs  = (const float*)d_in[9];
  float* out = (float*)d_out;

  // workspace: prm @0 (2KB) | pk4 @4096 (512KB) | sid @528384 (64KB)
  //            fidxG @593920 (1MB)
  float4* prm = (float4*)d_ws;
  float4* pk4 = (float4*)((char*)d_ws + 4096);
  unsigned short* sid = (unsigned short*)((char*)d_ws + 528384);
  unsigned short* fidxG = (unsigned short*)((char*)d_ws + 593920);

  hipLaunchKernelGGL(k_sort, dim3(5), dim3(1024), 0, stream,
                     xyz, w1, b1, w2, b2, w3, b3, pk4, sid, prm);
  hipLaunchKernelGGL(k_knn, dim3(B_ * 512), dim3(NTHR), 0, stream,
                     pk4, sid, fidxG);
  hipLaunchKernelGGL(k_epi, dim3(B_ * 512), dim3(256), 0, stream,
                     xyz, feature, prm, wsM, bs, fidxG, out);
}

// Round 9
// 304.759 us; speedup vs baseline: 1.0831x; 1.0831x over previous
//
#include <hip/hip_runtime.h>

#define B_ 4
#define N_ 8192
#define DIN 64
#define HDIM 64
#define DOUT 128
#define KNN 16
#define NBUCK 2048
#define QPB 16               // queries per block (kNN kernel)
#define QPW 4                // queries per wave
#define NTHR 256
#define BUFS 64              // survivor-buffer slots per query
#define NBATCH (N_ / 64)     // 128

__device__ __forceinline__ int mbcnt64(unsigned long long m) {
  return __builtin_amdgcn_mbcnt_hi((unsigned)(m >> 32),
         __builtin_amdgcn_mbcnt_lo((unsigned)m, 0));
}
// monotone float->uint map (total order, negatives below positives)
__device__ __forceinline__ unsigned mapkey(float d) {
  unsigned u = __float_as_uint(d);
  return (d < 0.0f) ? ~u : (u | 0x80000000u);
}
__device__ __forceinline__ float rf(float x) {  // force wave-uniform into SGPR
  return __int_as_float(__builtin_amdgcn_readfirstlane(__float_as_int(x)));
}

// Wave-cooperative exact 16 smallest by (key, original idx) among cnt slots.
// gout==null: compact kept 16 to slots 0..15, return kth distance (unmapped).
// gout!=null: write kept original idx to gout[rank] (global).
// Key radix narrowed to the differing-bit span (wave min/max prefix skip).
__device__ __forceinline__
float select16(unsigned* skQ, unsigned short* siQ, int cnt, unsigned short* gout) {
  const int l = threadIdx.x & 63;
  unsigned k = 0xFFFFFFFFu;
  unsigned mi = 0xFFFFu;
  if (l < cnt) { k = skQ[l]; mi = siQ[l]; }
  // narrow the radix span: common prefix of all 64 keys (pads included; they
  // are legit max-valued elements of the multiset, cnt>=16 real always)
  unsigned kmin = k, kmax = k;
  for (int off = 32; off; off >>= 1) {
    unsigned om = (unsigned)__shfl_xor((int)kmin, off);
    unsigned ox = (unsigned)__shfl_xor((int)kmax, off);
    kmin = kmin < om ? kmin : om;
    kmax = kmax > ox ? kmax : ox;
  }
  unsigned diff = kmin ^ kmax;
  unsigned p; int r = KNN;
  if (diff == 0u) {
    p = kmin;  // all keys equal -> pure tie case below
  } else {
    int hib = 31 - __builtin_clz(diff);
    unsigned pre = (hib == 31) ? 0u : (kmin & ~((1u << (hib + 1)) - 1u));
    p = pre;
    for (int bit = hib; bit >= 0; bit--) {
      unsigned long long ml = __ballot((int)(((k ^ p) >> bit) == 0u));
      int c0 = __popcll(ml);
      if (r > c0) { p |= (1u << bit); r -= c0; }
    }
  }
  bool isLT = (k < p), isTie = (k == p);
  int tieC = __popcll(__ballot((int)isTie));
  bool keepT = isTie;
  if (tieC != r) {  // break ties at the kth value by smallest ORIGINAL index
    unsigned mk = isTie ? mi : 0xFFFFFFFFu;
    unsigned p2 = 0; int r2 = r;
    for (int bit = 15; bit >= 0; bit--) {
      unsigned long long ml = __ballot((int)(((mk ^ p2) >> bit) == 0u));
      int c0 = __popcll(ml);
      if (r2 > c0) { p2 |= (1u << bit); r2 -= c0; }
    }
    keepT = isTie && (mi <= p2);
  }
  bool keep = isLT || keepT;
  unsigned long long km = __ballot((int)keep);
  int rank = mbcnt64(km);
  if (gout) {
    if (keep) gout[rank] = mi;
  } else {
    if (keep) { skQ[rank] = k; siQ[rank] = mi; }
  }
  unsigned fb = (p & 0x80000000u) ? (p & 0x7FFFFFFFu) : ~p;  // unmap
  return __uint_as_float(fb);
}

// ---------------- Kernel A: counting-sort by x + edges + affine params ---------
__global__ __launch_bounds__(1024) void k_sort(
    const float* __restrict__ xyz,
    const float* __restrict__ w1, const float* __restrict__ b1,
    const float* __restrict__ w2, const float* __restrict__ b2,
    const float* __restrict__ w3, const float* __restrict__ b3,
    float4* __restrict__ pk4, unsigned short* __restrict__ sid,
    float4* __restrict__ prm, float* __restrict__ eMinG,
    float* __restrict__ eMaxG) {
  const int t = threadIdx.x;
  __shared__ unsigned histA[NBUCK];
  __shared__ unsigned histB[NBUCK];
  __shared__ float rmm[32];

  if (blockIdx.x == 4) {  // ---- param composition ----
    float* M2 = (float*)histA;            // [64][10] floats
    float* bbv = (float*)histB;           // [64]
    if (t < HDIM) {
      float r[10];
#pragma unroll
      for (int c = 0; c < 10; c++) r[c] = 0.f;
      float s = b2[t];
      for (int l = 0; l < HDIM; l++) {
        float w = w2[t * HDIM + l];
#pragma unroll
        for (int c = 0; c < 10; c++) r[c] = fmaf(w, w1[l * 10 + c], r[c]);
        s = fmaf(w, b1[l], s);
      }
#pragma unroll
      for (int c = 0; c < 10; c++) M2[t * 10 + c] = r[c];
      bbv[t] = s;
    }
    __syncthreads();
    if (t < HDIM) {
      float r3[10];
#pragma unroll
      for (int c = 0; c < 10; c++) r3[c] = 0.f;
      float bc = b3[t];
      for (int l = 0; l < HDIM; l++) {
        float w = w3[t * HDIM + l];
#pragma unroll
        for (int c = 0; c < 10; c++) r3[c] = fmaf(w, M2[l * 10 + c], r3[c]);
        bc = fmaf(w, bbv[l], bc);
      }
      prm[t]      = make_float4(r3[0] - r3[6], r3[1] - r3[7], r3[2] - r3[8], bc);
      prm[64 + t] = make_float4(r3[3] + r3[6], r3[4] + r3[7], r3[5] + r3[8], r3[9]);
    }
    return;
  }

  // ---- sort batch b ----
  const int b = blockIdx.x;
  const float* xb = xyz + (size_t)b * 3 * N_;
  float xs[8];
  float lmin = 1e30f, lmax = -1e30f;
#pragma unroll
  for (int r = 0; r < 8; r++) {
    xs[r] = xb[r * 1024 + t];
    lmin = fminf(lmin, xs[r]); lmax = fmaxf(lmax, xs[r]);
  }
  for (int off = 32; off; off >>= 1) {
    lmin = fminf(lmin, __shfl_xor(lmin, off));
    lmax = fmaxf(lmax, __shfl_xor(lmax, off));
  }
  const int wid = t >> 6;
  if ((t & 63) == 0) { rmm[wid] = lmin; rmm[16 + wid] = lmax; }
  histA[t] = 0; histA[t + 1024] = 0;
  __syncthreads();
  if (t == 0) {
    float mn = rmm[0], mx = rmm[16];
    for (int w = 1; w < 16; w++) { mn = fminf(mn, rmm[w]); mx = fmaxf(mx, rmm[16 + w]); }
    rmm[0] = mn; rmm[16] = mx;
  }
  __syncthreads();
  const float mn = rmm[0];
  const float range = rmm[16] - mn;
  const float scale = (range > 0.f) ? ((float)NBUCK / range) : 0.f;
  int bk[8];
#pragma unroll
  for (int r = 0; r < 8; r++) {
    int v = (int)((xs[r] - mn) * scale);
    bk[r] = v > (NBUCK - 1) ? (NBUCK - 1) : (v < 0 ? 0 : v);
    atomicAdd(&histA[bk[r]], 1u);
  }
  __syncthreads();
  // exclusive scan (Hillis-Steele ping-pong)
  unsigned* src = histA; unsigned* dst = histB;
  for (int off = 1; off < NBUCK; off <<= 1) {
    for (int i = t; i < NBUCK; i += 1024) {
      unsigned v = src[i];
      if (i >= off) v += src[i - off];
      dst[i] = v;
    }
    __syncthreads();
    unsigned* tmp = src; src = dst; dst = tmp;
  }
  for (int i = t; i < NBUCK; i += 1024) dst[i] = i ? src[i - 1] : 0u;
  __syncthreads();
  // scatter
#pragma unroll
  for (int r = 0; r < 8; r++) {
    int m = r * 1024 + t;
    float x = xs[r], y = xb[N_ + m], z = xb[2 * N_ + m];
    float sq = __fadd_rn(__fadd_rn(__fmul_rn(x, x), __fmul_rn(y, y)), __fmul_rn(z, z));
    unsigned pos = atomicAdd(&dst[bk[r]], 1u);
    pk4[((size_t)b << 13) + pos] = make_float4(x, y, z, sq);
    sid[((size_t)b << 13) + pos] = (unsigned short)m;
  }
  __syncthreads();  // all scatter stores drained (vmcnt(0)) before edge reads
  if (t < NBATCH) {
    eMinG[b * NBATCH + t] = pk4[((size_t)b << 13) + t * 64].x;
    eMaxG[b * NBATCH + t] = pk4[((size_t)b << 13) + t * 64 + 63].x;
  }
}

// ---------------- Kernel B: windowed exact kNN, counted loops + prefetch -------
__global__ __launch_bounds__(NTHR, 8) void k_knn(
    const float4* __restrict__ pk4, const unsigned short* __restrict__ sid,
    const float* __restrict__ eMinG, const float* __restrict__ eMaxG,
    unsigned short* __restrict__ fidxG) {
  const int blk = blockIdx.x;
  const int b  = blk >> 9;
  const int s0 = (blk & 511) << 4;      // sorted-position base of this block
  const int t = threadIdx.x;
  const int lane = t & 63;
  const int j = __builtin_amdgcn_readfirstlane(t >> 6);
  const float4* pkb = pk4 + ((size_t)b << 13);
  const unsigned short* sdb = sid + ((size_t)b << 13);

  __shared__ unsigned skey[QPB * BUFS];        // 4 KB (rows owned per-wave)
  __shared__ unsigned short sidxS[QPB * BUFS]; // 2 KB
  __shared__ float eMin[NBATCH], eMax[NBATCH]; // 1 KB batch x-edges

  if (t < NBATCH) {
    eMin[t] = eMinG[b * NBATCH + t];
    eMax[t] = eMaxG[b * NBATCH + t];
  }

  float qX[QPW], qY[QPW], qZ[QPW], qS[QPW]; int qN[QPW];
#pragma unroll
  for (int i = 0; i < QPW; i++) {
    int p = s0 + j * QPW + i;
    float4 qv = pkb[p];
    qX[i] = rf(qv.x); qY[i] = rf(qv.y); qZ[i] = rf(qv.z); qS[i] = rf(qv.w);
    qN[i] = __builtin_amdgcn_readfirstlane((int)sdb[p]);
  }
  const float qxmin = fminf(fminf(qX[0], qX[1]), fminf(qX[2], qX[3]));
  const float qxmax = fmaxf(fmaxf(qX[0], qX[1]), fmaxf(qX[2], qX[3]));
  float tauF[QPW]; int cntA[QPW];
  __syncthreads();  // edges visible

  auto process = [&](float4 c, unsigned short mid) {
    float dd[QPW];
#pragma unroll
    for (int i = 0; i < QPW; i++) {
      float dot = fmaf(c.z, qZ[i], fmaf(c.y, qY[i], __fmul_rn(c.x, qX[i])));
      dd[i] = fmaf(-2.0f, dot, __fadd_rn(qS[i], c.w));
    }
#pragma unroll
    for (int i = 0; i < QPW; i++) {
      bool mine = dd[i] <= tauF[i];   // <= : out-of-order scan must keep ties
      unsigned long long hit = __ballot((int)mine);
      if (hit) {
        unsigned* skQ = skey + (j * QPW + i) * BUFS;
        unsigned short* siQ = sidxS + (j * QPW + i) * BUFS;
        int h = __popcll(hit);
        int rk = mbcnt64(hit);
        unsigned key = mapkey(dd[i]);
        if (cntA[i] + h <= BUFS) {  // fast path
          if (mine) { skQ[cntA[i] + rk] = key; siQ[cntA[i] + rk] = mid; }
          cntA[i] += h;
          if (cntA[i] == BUFS) {
            tauF[i] = rf(select16(skQ, siQ, BUFS, nullptr));
            cntA[i] = KNN;
          }
        } else {  // overflow: rounds, compacting (guaranteed shrink to 16)
          unsigned long long rem = hit; bool mrem = mine;
          while (rem) {
            int freeS = BUFS - cntA[i];
            int hh = __popcll(rem);
            int rr = mbcnt64(rem);
            bool wn = mrem && (rr < freeS);
            if (wn) { skQ[cntA[i] + rr] = key; siQ[cntA[i] + rr] = mid; }
            cntA[i] += (hh < freeS) ? hh : freeS;
            if (cntA[i] == BUFS) {
              tauF[i] = rf(select16(skQ, siQ, BUFS, nullptr));
              cntA[i] = KNN;
            }
            mrem = mrem && !wn && (dd[i] <= tauF[i]);
            rem = __ballot((int)mrem);
          }
        }
      }
    }
  };

  const int hb = s0 >> 6;  // home batch (block's 16 queries all inside it)
  {  // unconditional fill from the home batch, then first exact tau
    float4 c = pkb[hb * 64 + lane];
    unsigned short mid = sdb[hb * 64 + lane];
#pragma unroll
    for (int i = 0; i < QPW; i++) {
      float dot = fmaf(c.z, qZ[i], fmaf(c.y, qY[i], __fmul_rn(c.x, qX[i])));
      float d = fmaf(-2.0f, dot, __fadd_rn(qS[i], c.w));
      skey[(j * QPW + i) * BUFS + lane] = mapkey(d);
      sidxS[(j * QPW + i) * BUFS + lane] = mid;
    }
#pragma unroll
    for (int i = 0; i < QPW; i++) {
      tauF[i] = rf(select16(skey + (j * QPW + i) * BUFS,
                            sidxS + (j * QPW + i) * BUFS, BUFS, nullptr));
      cntA[i] = KNN;
    }
  }

  {  // left sweep: near -> far, depth-1 prefetch, dynamic exact close
    int pb = hb - 1;
    float4 pc; unsigned short pm;
    if (pb >= 0) { pc = pkb[pb * 64 + lane]; pm = sdb[pb * 64 + lane]; }
    while (pb >= 0) {
      float tmax = fmaf(fmaxf(fmaxf(tauF[0], tauF[1]), fmaxf(tauF[2], tauF[3])),
                        1.0001f, 1e-5f);
      float gap = __fsub_rn(qxmin, eMax[pb]);
      if (gap > 0.f && __fmul_rn(gap, gap) > tmax) break;
      float4 c = pc; unsigned short mid = pm;
      if (pb - 1 >= 0) { pc = pkb[(pb - 1) * 64 + lane]; pm = sdb[(pb - 1) * 64 + lane]; }
      process(c, mid);
      --pb;
    }
  }
  {  // right sweep
    int pb = hb + 1;
    float4 pc; unsigned short pm;
    if (pb < NBATCH) { pc = pkb[pb * 64 + lane]; pm = sdb[pb * 64 + lane]; }
    while (pb < NBATCH) {
      float tmax = fmaf(fmaxf(fmaxf(tauF[0], tauF[1]), fmaxf(tauF[2], tauF[3])),
                        1.0001f, 1e-5f);
      float gap = __fsub_rn(eMin[pb], qxmax);
      if (gap > 0.f && __fmul_rn(gap, gap) > tmax) break;
      float4 c = pc; unsigned short mid = pm;
      if (pb + 1 < NBATCH) { pc = pkb[(pb + 1) * 64 + lane]; pm = sdb[(pb + 1) * 64 + lane]; }
      process(c, mid);
      ++pb;
    }
  }
  // final exact selection -> global neighbor ids at the ORIGINAL query slot
#pragma unroll
  for (int i = 0; i < QPW; i++) {
    select16(skey + (j * QPW + i) * BUFS, sidxS + (j * QPW + i) * BUFS,
             cntA[i], fidxG + ((((size_t)b << 13) + qN[i]) << 4));
  }
}

// ---------------- Kernel C: epilogue (gather, fe, shortcut GEMM, store) --------
__global__ __launch_bounds__(256, 8) void k_epi(
    const float* __restrict__ xyz, const float* __restrict__ feature,
    const float4* __restrict__ prm, const float* __restrict__ wsM,
    const float* __restrict__ bs, const unsigned short* __restrict__ fidxG,
    float* __restrict__ out) {
  const int blk = blockIdx.x;
  const int b  = blk >> 9;
  const int n0 = (blk & 511) << 4;
  const int t = threadIdx.x;
  const int q = t & 15;
  const int g = t >> 4;
  const float* xb = xyz + (size_t)b * 3 * N_;
  const float INF = __uint_as_float(0x7f800000u);

  __shared__ float nb[64 * 16];    // neighbor x/y/z/dsq rows
  __shared__ float feFe[64 * 16];  // fe channels
  __shared__ float feL[64 * 16];   // feature tile

  const float qx = xb[n0 + q], qy = xb[N_ + n0 + q], qz = xb[2 * N_ + n0 + q];
  {  // gather: thread handles neighbor slot k=g for query q
    int m = fidxG[((((size_t)b << 13) + n0 + q) << 4) + g];
    float x = xb[m], y = xb[N_ + m], z = xb[2 * N_ + m];
    float dx = __fsub_rn(x, qx), dy = __fsub_rn(y, qy), dz = __fsub_rn(z, qz);
    float dsq = __fadd_rn(__fadd_rn(__fmul_rn(dx, dx), __fmul_rn(dy, dy)),
                          __fmul_rn(dz, dz));
    nb[g * 16 + q] = x;
    nb[(16 + g) * 16 + q] = y;
    nb[(32 + g) * 16 + q] = z;
    nb[(48 + g) * 16 + q] = dsq;
  }
  __syncthreads();

  {  // fe: thread computes channels c = g*4..+3 for query q
    float mx0 = -INF, mx1 = -INF, mx2 = -INF, mx3 = -INF;
    const int c0 = g * 4;
    float4 pB0 = prm[64 + c0], pB1 = prm[64 + c0 + 1];
    float4 pB2 = prm[64 + c0 + 2], pB3 = prm[64 + c0 + 3];
#pragma unroll
    for (int k = 0; k < KNN; k++) {
      float nx = nb[k * 16 + q], ny = nb[(16 + k) * 16 + q];
      float nz = nb[(32 + k) * 16 + q], nd = nb[(48 + k) * 16 + q];
      mx0 = fmaxf(mx0, fmaf(nz, pB0.z, fmaf(ny, pB0.y, fmaf(nx, pB0.x, __fmul_rn(nd, pB0.w)))));
      mx1 = fmaxf(mx1, fmaf(nz, pB1.z, fmaf(ny, pB1.y, fmaf(nx, pB1.x, __fmul_rn(nd, pB1.w)))));
      mx2 = fmaxf(mx2, fmaf(nz, pB2.z, fmaf(ny, pB2.y, fmaf(nx, pB2.x, __fmul_rn(nd, pB2.w)))));
      mx3 = fmaxf(mx3, fmaf(nz, pB3.z, fmaf(ny, pB3.y, fmaf(nx, pB3.x, __fmul_rn(nd, pB3.w)))));
    }
    float4 pA0 = prm[c0], pA1 = prm[c0 + 1], pA2 = prm[c0 + 2], pA3 = prm[c0 + 3];
    feFe[(c0 + 0) * 16 + q] = fmaf(qz, pA0.z, fmaf(qy, pA0.y, fmaf(qx, pA0.x, pA0.w))) + mx0;
    feFe[(c0 + 1) * 16 + q] = fmaf(qz, pA1.z, fmaf(qy, pA1.y, fmaf(qx, pA1.x, pA1.w))) + mx1;
    feFe[(c0 + 2) * 16 + q] = fmaf(qz, pA2.z, fmaf(qy, pA2.y, fmaf(qx, pA2.x, pA2.w))) + mx2;
    feFe[(c0 + 3) * 16 + q] = fmaf(qz, pA3.z, fmaf(qy, pA3.y, fmaf(qx, pA3.x, pA3.w))) + mx3;
  }
#pragma unroll
  for (int ci = 0; ci < 4; ci++) {
    int c = g * 4 + ci;
    feL[c * 16 + q] = feature[(size_t)(b * DIN + c) * N_ + n0 + q];
  }
  __syncthreads();

  // shortcut GEMM: thread computes outputs o = g*8..+7 for query q
  float acc[8];
#pragma unroll
  for (int oi = 0; oi < 8; oi++) acc[oi] = 0.f;
  const float4* wsRow = (const float4*)(wsM + (size_t)g * 8 * DIN);
  for (int c4 = 0; c4 < DIN / 4; c4++) {
    float f0 = feL[(4 * c4 + 0) * 16 + q];
    float f1 = feL[(4 * c4 + 1) * 16 + q];
    float f2 = feL[(4 * c4 + 2) * 16 + q];
    float f3 = feL[(4 * c4 + 3) * 16 + q];
#pragma unroll
    for (int oi = 0; oi < 8; oi++) {
      float4 w = wsRow[oi * (DIN / 4) + c4];  // group-uniform, L1-resident
      acc[oi] = fmaf(w.x, f0, acc[oi]);
      acc[oi] = fmaf(w.y, f1, acc[oi]);
      acc[oi] = fmaf(w.z, f2, acc[oi]);
      acc[oi] = fmaf(w.w, f3, acc[oi]);
    }
  }
  float* ob = out + (size_t)b * DOUT * N_ + n0 + q;
#pragma unroll
  for (int oi = 0; oi < 8; oi++) {
    int o = g * 8 + oi;
    ob[(size_t)o * N_] = acc[oi] + bs[o] + feFe[(o & 63) * 16 + q];
  }
}

extern "C" void kernel_launch(void* const* d_in, const int* in_sizes, int n_in,
                              void* d_out, int out_size, void* d_ws, size_t ws_size,
                              hipStream_t stream) {
  const float* xyz     = (const float*)d_in[0];
  const float* feature = (const float*)d_in[1];
  const float* w1 = (const float*)d_in[2];
  const float* b1 = (const float*)d_in[3];
  const float* w2 = (const float*)d_in[4];
  const float* b2 = (const float*)d_in[5];
  const float* w3 = (const float*)d_in[6];
  const float* b3 = (const float*)d_in[7];
  const float* wsM = (const float*)d_in[8];
  const float* bs  = (const float*)d_in[9];
  float* out = (float*)d_out;

  // workspace: prm @0 (2KB) | pk4 @4096 (512KB) | sid @528384 (64KB)
  //            fidxG @593920 (1MB) | eMin @1642496 (2KB) | eMax @1644544 (2KB)
  float4* prm = (float4*)d_ws;
  float4* pk4 = (float4*)((char*)d_ws + 4096);
  unsigned short* sid = (unsigned short*)((char*)d_ws + 528384);
  unsigned short* fidxG = (unsigned short*)((char*)d_ws + 593920);
  float* eMinG = (float*)((char*)d_ws + 1642496);
  float* eMaxG = (float*)((char*)d_ws + 1644544);

  hipLaunchKernelGGL(k_sort, dim3(5), dim3(1024), 0, stream,
                     xyz, w1, b1, w2, b2, w3, b3, pk4, sid, prm, eMinG, eMaxG);
  hipLaunchKernelGGL(k_knn, dim3(B_ * 512), dim3(NTHR), 0, stream,
                     pk4, sid, eMinG, eMaxG, fidxG);
  hipLaunchKernelGGL(k_epi, dim3(B_ * 512), dim3(256), 0, stream,
                     xyz, feature, prm, wsM, bs, fidxG, out);
}